// Round 6
// baseline (123.301 us; speedup 1.0000x reference)
//
#include <hip/hip_runtime.h>

#define NTY 50
#define NCA 20
#define ED  64
#define NB  4
#define SL  256

#define TYPE_BLOCKS (NB * NTY)   // 200: one per (batch, target type)
#define CAT_BLOCKS  (NB * NCA)   // 80:  one per (batch, target category)
#define MAIN_BLOCKS (TYPE_BLOCKS + CAT_BLOCKS)
#define CHK 8                    // events reduced per barrier pair

// ws float layout — every slot has exactly ONE writer, no zero-init needed:
#define WS_M  0                        // [NB][SL] per-event type-channel partial
#define WS_N  (NB * SL)                // [NB][SL] per-event cat-channel partial
#define WS_IT (2 * NB * SL)            // [NB][NTY] horizon type partial
#define WS_NT (2 * NB * SL + NB * NTY) // [NB][ED] horizon cat n-vector

__device__ __forceinline__ float softplusf(float x) {
    return (x > 0.f) ? x + log1pf(__expf(-x)) : log1pf(__expf(x));
}

__device__ __forceinline__ float waveReduceSum(float v) {
    #pragma unroll
    for (int off = 32; off > 0; off >>= 1) v += __shfl_down(v, off, 64);
    return v;
}

struct SB {
    float2 cr[NTY * ED];      // {C,R}: C=tr*A*f, R=tr*P*f (cat uses 20 rows) 25.6 KB
    float  tsh[SL + 1];       // [SL] = horizon T (virtual event)
    int    ysh[SL];
    int    csh[SL];
    int    evl[SL];
    int    evcnt;
    float  red[CHK][4][ED];   // 8 KB
};

// Block per (batch, target): ONE table staging serves all ~5 events with that
// target (6x less staging than block-per-event), inner loop stays the dense
// round-5 form: 1 ds_read_b64 + 1 exp per (event,source,lane). No CSR/prefix.
__global__ __launch_bounds__(256) void hawkes_main(
        const float* __restrict__ times,
        const int*   __restrict__ types,
        const int*   __restrict__ cats,
        const int*   __restrict__ Tp,
        const float* __restrict__ type_emb,
        const float* __restrict__ cat_emb,
        const float* __restrict__ amat,
        const float* __restrict__ bmat,
        const float* __restrict__ A,
        const float* __restrict__ P,
        const float* __restrict__ Bm,
        const float* __restrict__ Q,
        float* __restrict__ ws) {
    const int blk  = blockIdx.x;
    const int tid  = threadIdx.x;
    const int lane = tid & 63;
    const int w    = tid >> 6;
    __shared__ SB sh;

    const float Tf = (float)Tp[0];
    const bool isType = blk < TYPE_BLOCKS;
    const int  b    = isType ? blk / NTY : (blk - TYPE_BLOCKS) / NCA;
    const int  tgt  = isType ? blk % NTY : (blk - TYPE_BLOCKS) % NCA;
    const int  base = b * SL;

    // ---- stage sequences ----
    if (tid < SL) {
        sh.tsh[tid] = times[base + tid];
        sh.ysh[tid] = types[base + tid];
        sh.csh[tid] = cats[base + tid];
    }
    if (tid == 0) sh.tsh[SL] = Tf;

    // ---- stage the one {C,R} table this block ever needs ----
    if (isType) {
        for (int idx = tid; idx < NTY * ED; idx += 256) {
            const int e = idx & 63, k = idx >> 6;
            const float tr = type_emb[tgt * ED + e];
            const float f  = type_emb[idx];
            sh.cr[idx] = make_float2(tr * A[(k * NTY + tgt) * ED + e] * f,
                                     tr * P[(k * NTY + tgt) * ED + e] * f);
        }
    } else {
        for (int idx = tid; idx < NCA * ED; idx += 256) {
            const int e = idx & 63, k = idx >> 6;
            const float cr = cat_emb[tgt * ED + e];
            const float g  = cat_emb[idx];
            sh.cr[idx] = make_float2(cr * Bm[(k * NCA + tgt) * ED + e] * g,
                                     cr * Q [(k * NCA + tgt) * ED + e] * g);
        }
    }
    __syncthreads();

    // ---- wave 0: ordered compaction of this block's event positions ----
    if (w == 0) {
        int run = 0;
        #pragma unroll
        for (int c = 0; c < SL / 64; ++c) {
            const int p = lane + 64 * c;
            const bool pred = (p >= 1) && (isType ? (sh.ysh[p] == tgt)
                                                  : (sh.csh[p - 1] == tgt));
            const unsigned long long mk = __ballot(pred);
            if (pred) sh.evl[run + __popcll(mk & ((1ull << lane) - 1ull))] = p;
            run += __popcll(mk);
        }
        if (lane == 0) sh.evcnt = run;
    }
    __syncthreads();

    const int  ne    = sh.evcnt;
    const int  lastc = sh.csh[SL - 1];
    const bool doHor = isType || (tgt == lastc);
    const int  nev   = ne + (doHor ? 1 : 0);      // real events + virtual horizon

    float teL = 0.f, aL = 0.f;
    if (isType) {
        teL = type_emb[tgt * ED + lane];
        aL  = amat[tgt * ED + lane];
    }

    for (int j0 = 0; j0 < nev; j0 += CHK) {
        const int jmax = min(CHK, nev - j0);

        // ---- per-wave source partials for up to CHK events ----
        for (int jj = 0; jj < jmax; ++jj) {
            const int j  = j0 + jj;
            const int ie = (j < ne) ? sh.evl[j] : SL;
            const float tau = sh.tsh[ie];
            float acc = 0.f;
            #pragma unroll 4
            for (int s = w; s < ie; s += 4) {
                const float td = tau - sh.tsh[s];
                const float2 ar = sh.cr[(isType ? sh.ysh[s] : sh.csh[s]) * ED + lane];
                acc += ar.x * __expf(-ar.y * td);
            }
            sh.red[jj][w][lane] = acc;
        }
        __syncthreads();

        // ---- cross-wave reduce: wave w owns events jj = w, w+4 ----
        for (int jj = w; jj < jmax; jj += 4) {
            const int j  = j0 + jj;
            const int ie = (j < ne) ? sh.evl[j] : SL;
            float v = sh.red[jj][0][lane] + sh.red[jj][1][lane]
                    + sh.red[jj][2][lane] + sh.red[jj][3][lane];
            if (isType) {
                if (j < ne) {
                    v += teL * (aL + bmat[sh.csh[ie - 1] * ED + lane]);
                    const float r = waveReduceSum(v);
                    if (lane == 0) ws[WS_M + b * SL + ie] = r;
                } else {
                    v += teL * aL;
                    const float r = waveReduceSum(v);
                    if (lane == 0) ws[WS_IT + b * NTY + tgt] = r;
                }
            } else {
                if (j < ne) {
                    const float r = waveReduceSum(v * type_emb[sh.ysh[ie] * ED + lane]);
                    if (lane == 0) ws[WS_N + b * SL + ie] = r;
                } else {
                    ws[WS_NT + b * ED + lane] = v;   // per-lane n_T store
                }
            }
        }
        __syncthreads();
    }
}

__global__ __launch_bounds__(256) void hawkes_final(
        const float* __restrict__ times,
        const int*   __restrict__ types,
        const int*   __restrict__ cats,
        const int*   __restrict__ Tp,
        const float* __restrict__ type_emb,
        const float* __restrict__ amat,
        const float* __restrict__ bmat,
        const float* __restrict__ ws,
        float* __restrict__ out) {
    const int tid  = threadIdx.x;
    const int lane = tid & 63;
    const int w    = tid >> 6;          // wave w also owns batch w

    __shared__ float tsl[4][ED];
    __shared__ float wred[4], i0red[4], intb[4];

    const float Tf = (float)Tp[0];

    // ---- log-likelihood over events i>=1 (thread tid -> i=tid+1, all batches) ----
    float llp = 0.f;
    const int i = tid + 1;
    if (i < SL) {
        #pragma unroll
        for (int bb = 0; bb < NB; ++bb) {
            const float lam = ws[WS_M + bb * SL + i] + ws[WS_N + bb * SL + i];
            llp += logf(lam + 1e-16f) + lam;
        }
    }

    // ---- empty-history lambda_0 for batch w ----
    const int t0 = types[w * SL];
    const float v0 = softplusf(type_emb[t0 * ED + lane] * amat[t0 * ED + lane]);

    // ---- TS[e] = sum_t te[t,e] and I0, t split by wave ----
    float tsp = 0.f, i0p = 0.f;
    for (int t = w; t < NTY; t += 4) {
        const float tv = type_emb[t * ED + lane];
        tsp += tv;
        i0p += softplusf(tv * amat[t * ED + lane]);
    }
    tsl[w][lane] = tsp;

    const float lam0 = waveReduceSum(v0);
    const float wll  = waveReduceSum(llp);
    const float wi0  = waveReduceSum(i0p);
    if (lane == 0) {
        wred[w]  = wll + logf(lam0 + 1e-16f) + lam0;
        i0red[w] = wi0;
    }
    __syncthreads();

    // ---- horizon integral for batch w ----
    const float TS_l = tsl[0][lane] + tsl[1][lane] + tsl[2][lane] + tsl[3][lane];
    const int   lc   = cats[w * SL + SL - 1];
    const float bbv  = bmat[lc * ED + lane] + ws[WS_NT + w * ED + lane];
    const float its  = (lane < NTY) ? ws[WS_IT + w * NTY + lane] : 0.f;
    const float ip   = waveReduceSum(its + bbv * TS_l);
    if (lane == 0) intb[w] = ip * (Tf - times[w * SL + SL - 1]);
    __syncthreads();

    if (tid == 0) {
        const float ll  = wred[0] + wred[1] + wred[2] + wred[3];
        const float I0  = i0red[0] + i0red[1] + i0red[2] + i0red[3];
        const float t0s = times[0] + times[SL] + times[2 * SL] + times[3 * SL];
        const float tot = intb[0] + intb[1] + intb[2] + intb[3] + I0 * t0s;
        out[0] = -(ll - tot);
    }
}

extern "C" void kernel_launch(void* const* d_in, const int* in_sizes, int n_in,
                              void* d_out, int out_size, void* d_ws, size_t ws_size,
                              hipStream_t stream) {
    const float* times    = (const float*)d_in[0];
    const int*   types    = (const int*)  d_in[1];
    const int*   cats     = (const int*)  d_in[2];
    const int*   Tp       = (const int*)  d_in[3];
    const float* type_emb = (const float*)d_in[4];
    const float* cat_emb  = (const float*)d_in[5];
    const float* amat     = (const float*)d_in[6];
    const float* bmat     = (const float*)d_in[7];
    const float* A        = (const float*)d_in[8];
    const float* P        = (const float*)d_in[9];
    const float* Bm       = (const float*)d_in[10];
    const float* Q        = (const float*)d_in[11];
    float* out = (float*)d_out;
    float* ws  = (float*)d_ws;

    // No memset: every ws slot read by hawkes_final is written exactly once.
    hawkes_main<<<MAIN_BLOCKS, 256, 0, stream>>>(times, types, cats, Tp,
                                                 type_emb, cat_emb, amat, bmat,
                                                 A, P, Bm, Q, ws);
    hawkes_final<<<1, 256, 0, stream>>>(times, types, cats, Tp,
                                        type_emb, amat, bmat, ws, out);
}

// Round 7
// 112.814 us; speedup vs baseline: 1.0930x; 1.0930x over previous
//
#include <hip/hip_runtime.h>

#define NTY 50
#define NCA 20
#define ED  64
#define NB  4
#define SL  256

#define TH_BLOCKS (NB * NTY * 2)            // 400: (batch, type, half)
#define CQ_BLOCKS (NB * NCA * 4)            // 320: (batch, cat, quarter)
#define MAIN_BLOCKS (TH_BLOCKS + CQ_BLOCKS) // 720
#define NTHREADS 512
#define ECHK 32

// ws float planes — every slot has exactly ONE writer, no zero-init needed:
#define WS_M  0                             // [2][NB][SL]  type partial, per half
#define WS_N  (2 * NB * SL)                 // [4][NB][SL]  cat partial, per quarter
#define WS_IT (WS_N + 4 * NB * SL)          // [2][NB][NTY] horizon type, per half
#define WS_NT (WS_IT + 2 * NB * NTY)        // [4][NB][ED]  horizon cat vec, per quarter

__device__ __forceinline__ float softplusf(float x) {
    return (x > 0.f) ? x + log1pf(__expf(-x)) : log1pf(__expf(x));
}

__device__ __forceinline__ float waveReduceSum(float v) {
    #pragma unroll
    for (int off = 32; off > 0; off >>= 1) v += __shfl_down(v, off, 64);
    return v;
}

struct SB {
    float2 cr[NTY * ED];     // {C,R}: C=tr*A*f, R=tr*P*f (cat uses 20 rows) 25.6 KB
    float  tsh[SL + 1];      // [SL] = horizon T (virtual event)
    int    ysh[SL];
    int    csh[SL];
    int    evl[SL];
    int    evcnt;
    float  red[ECHK][8];     // per-(event, wave) scalar partials
    float  redv[8][ED];      // cat-horizon per-wave vectors
};

// Latency-engineered shape: 720 blocks x 8 waves (5.6 waves/SIMD for hiding),
// staging = load-all-then-write-all (one exposure), inner iter = 1 uniform
// LDS read + 1 ds_read_b64 (+exp+fma). Outputs go to single-writer planes.
template <bool IS_TYPE, int NK, int NSPLIT>
__device__ __forceinline__ void run_channel(
        int b, int tgt, int part, int tid,
        const float* __restrict__ times, const int* __restrict__ types,
        const int* __restrict__ cats, float Tf,
        const float* __restrict__ type_emb, const float* __restrict__ cat_emb,
        const float* __restrict__ amat, const float* __restrict__ bmat,
        const float* __restrict__ Cmat, const float* __restrict__ Pmat,
        float* __restrict__ ws, SB& sh) {
    const int lane = tid & 63;
    const int w    = tid >> 6;
    const int base = b * SL;
    constexpr int FR   = (NK + 7) / 8;   // staging frames: k = fr*8 + w
    constexpr int SRCN = SL / NSPLIT;    // sources owned by this slice
    const int s_lo = part * SRCN;
    const int s_hi = s_lo + SRCN;

    const float* EMB = IS_TYPE ? type_emb : cat_emb;

    // ---- seq staging (first 256 threads, coalesced, same exposure) ----
    if (tid < SL) {
        sh.tsh[tid] = times[base + tid];
        sh.ysh[tid] = types[base + tid];
        sh.csh[tid] = cats[base + tid];
    }
    if (tid == 0) sh.tsh[SL] = Tf;

    // ---- table staging: cluster ALL loads, then ALL writes (one exposure) ----
    // e = lane (frame*512 = 0 mod 64), k = fr*8 + w  -> coalesced rows
    const float trv = EMB[tgt * ED + lane];
    float rA[FR], rP[FR], rF[FR];
    #pragma unroll
    for (int fr = 0; fr < FR; ++fr) {
        const int k = fr * 8 + w;
        if (k < NK) {
            rA[fr] = Cmat[(k * NK + tgt) * ED + lane];
            rP[fr] = Pmat[(k * NK + tgt) * ED + lane];
            rF[fr] = EMB[k * ED + lane];
        }
    }
    #pragma unroll
    for (int fr = 0; fr < FR; ++fr) {
        const int k = fr * 8 + w;
        if (k < NK)
            sh.cr[k * ED + lane] = make_float2(trv * rA[fr] * rF[fr],
                                               trv * rP[fr] * rF[fr]);
    }
    __syncthreads();

    // ---- wave 0: ordered compaction of this slice's event positions ----
    if (w == 0) {
        int run = 0;
        #pragma unroll
        for (int c = 0; c < SL / 64; ++c) {
            const int p = lane + 64 * c;
            const bool pred = (p >= 1) && (IS_TYPE ? (sh.ysh[p] == tgt)
                                                   : (sh.csh[p - 1] == tgt));
            const unsigned long long mk = __ballot(pred);
            if (pred) sh.evl[run + __popcll(mk & ((1ull << lane) - 1ull))] = p;
            run += __popcll(mk);
        }
        if (lane == 0) sh.evcnt = run;
    }
    __syncthreads();

    const int ne    = sh.evcnt;
    const int nev   = ne + 1;                 // + virtual horizon event
    const int lastc = sh.csh[SL - 1];
    const int* keys = IS_TYPE ? sh.ysh : sh.csh;
    float trL = 0.f, aL = 0.f;
    if (IS_TYPE) { trL = trv; aL = amat[tgt * ED + lane]; }

    for (int j0 = 0; j0 < nev; j0 += ECHK) {
        const int jmax = min(ECHK, nev - j0);

        // ---- emit: per-wave source partial over this slice's range ----
        for (int jj = 0; jj < jmax; ++jj) {
            const int j  = j0 + jj;
            const int ie = (j < ne) ? sh.evl[j] : SL;
            const int hi = min(ie, s_hi);
            const float tau = sh.tsh[ie];
            float acc = 0.f;
            #pragma unroll 4
            for (int s = s_lo + w; s < hi; s += 8) {
                const float td = tau - sh.tsh[s];
                const float2 crv = sh.cr[keys[s] * ED + lane];
                acc += crv.x * __expf(-crv.y * td);
            }
            if (IS_TYPE) {
                const float r = waveReduceSum(acc);
                if (lane == 0) sh.red[jj][w] = r;
            } else if (j < ne) {
                const float te_l = type_emb[sh.ysh[ie] * ED + lane];
                const float r = waveReduceSum(acc * te_l);
                if (lane == 0) sh.red[jj][w] = r;
            } else {
                sh.redv[w][lane] = acc;      // cat horizon: keep per-e vector
            }
        }
        __syncthreads();

        // ---- finalize: wave w owns events jj = w (mod 8) ----
        for (int jj = w; jj < jmax; jj += 8) {
            const int j = j0 + jj;
            if (!IS_TYPE && j == ne) continue;      // handled via redv
            const int ie = (j < ne) ? sh.evl[j] : SL;
            float s8 = 0.f;
            #pragma unroll
            for (int u = 0; u < 8; ++u) s8 += sh.red[jj][u];
            if (IS_TYPE) {
                float r = s8;
                if (part == 0) {                    // base terms once (half 0)
                    const float v = (j < ne)
                        ? trL * (aL + bmat[sh.csh[ie - 1] * ED + lane])
                        : trL * aL;
                    r += waveReduceSum(v);
                }
                if (lane == 0) {
                    if (j < ne) ws[WS_M + (part * NB + b) * SL + ie] = r;
                    else        ws[WS_IT + (part * NB + b) * NTY + tgt] = r;
                }
            } else {
                if (lane == 0) ws[WS_N + (part * NB + b) * SL + ie] = s8;
            }
        }
        __syncthreads();
    }

    // ---- cat horizon n-vector plane (only the last_cat target writes) ----
    if (!IS_TYPE && tgt == lastc && w == 0) {
        float nv = 0.f;
        #pragma unroll
        for (int u = 0; u < 8; ++u) nv += sh.redv[u][lane];
        ws[WS_NT + (part * NB + b) * ED + lane] = nv;
    }
}

__global__ __launch_bounds__(NTHREADS) void hawkes_main(
        const float* __restrict__ times,
        const int*   __restrict__ types,
        const int*   __restrict__ cats,
        const int*   __restrict__ Tp,
        const float* __restrict__ type_emb,
        const float* __restrict__ cat_emb,
        const float* __restrict__ amat,
        const float* __restrict__ bmat,
        const float* __restrict__ A,
        const float* __restrict__ P,
        const float* __restrict__ Bm,
        const float* __restrict__ Q,
        float* __restrict__ ws) {
    const int blk = blockIdx.x;
    const int tid = threadIdx.x;
    __shared__ SB sh;

    const float Tf = (float)Tp[0];

    if (blk < TH_BLOCKS) {
        const int b = blk / (NTY * 2);
        const int rem = blk % (NTY * 2);
        run_channel<true, NTY, 2>(b, rem >> 1, rem & 1, tid,
                                  times, types, cats, Tf,
                                  type_emb, cat_emb, amat, bmat, A, P, ws, sh);
    } else {
        const int r = blk - TH_BLOCKS;
        const int b = r / (NCA * 4);
        const int rem = r % (NCA * 4);
        run_channel<false, NCA, 4>(b, rem >> 2, rem & 3, tid,
                                   times, types, cats, Tf,
                                   type_emb, cat_emb, amat, bmat, Bm, Q, ws, sh);
    }
}

__global__ __launch_bounds__(256) void hawkes_final(
        const float* __restrict__ times,
        const int*   __restrict__ types,
        const int*   __restrict__ cats,
        const int*   __restrict__ Tp,
        const float* __restrict__ type_emb,
        const float* __restrict__ amat,
        const float* __restrict__ bmat,
        const float* __restrict__ ws,
        float* __restrict__ out) {
    const int tid  = threadIdx.x;
    const int lane = tid & 63;
    const int w    = tid >> 6;          // wave w also owns batch w

    __shared__ float tsl[4][ED];
    __shared__ float wred[4], i0red[4], intb[4];

    const float Tf = (float)Tp[0];

    // ---- log-likelihood over events i>=1: sum the planes ----
    float llp = 0.f;
    const int i = tid + 1;
    if (i < SL) {
        #pragma unroll
        for (int bb = 0; bb < NB; ++bb) {
            float lam = ws[WS_M + bb * SL + i] + ws[WS_M + (NB + bb) * SL + i];
            #pragma unroll
            for (int q = 0; q < 4; ++q) lam += ws[WS_N + (q * NB + bb) * SL + i];
            llp += logf(lam + 1e-16f) + lam;
        }
    }

    // ---- empty-history lambda_0 for batch w ----
    const int t0 = types[w * SL];
    const float v0 = softplusf(type_emb[t0 * ED + lane] * amat[t0 * ED + lane]);

    // ---- TS[e] = sum_t te[t,e] and I0, t split by wave ----
    float tsp = 0.f, i0p = 0.f;
    for (int t = w; t < NTY; t += 4) {
        const float tv = type_emb[t * ED + lane];
        tsp += tv;
        i0p += softplusf(tv * amat[t * ED + lane]);
    }
    tsl[w][lane] = tsp;

    const float lam0 = waveReduceSum(v0);
    const float wll  = waveReduceSum(llp);
    const float wi0  = waveReduceSum(i0p);
    if (lane == 0) {
        wred[w]  = wll + logf(lam0 + 1e-16f) + lam0;
        i0red[w] = wi0;
    }
    __syncthreads();

    // ---- horizon integral for batch w ----
    const float TS_l = tsl[0][lane] + tsl[1][lane] + tsl[2][lane] + tsl[3][lane];
    const int   lc   = cats[w * SL + SL - 1];
    float nT = 0.f;
    #pragma unroll
    for (int q = 0; q < 4; ++q) nT += ws[WS_NT + (q * NB + w) * ED + lane];
    const float bbv = bmat[lc * ED + lane] + nT;
    float its = 0.f;
    if (lane < NTY) {
        its = ws[WS_IT + w * NTY + lane] + ws[WS_IT + (NB + w) * NTY + lane];
    }
    const float ip = waveReduceSum(its + bbv * TS_l);
    if (lane == 0) intb[w] = ip * (Tf - times[w * SL + SL - 1]);
    __syncthreads();

    if (tid == 0) {
        const float ll  = wred[0] + wred[1] + wred[2] + wred[3];
        const float I0  = i0red[0] + i0red[1] + i0red[2] + i0red[3];
        const float t0s = times[0] + times[SL] + times[2 * SL] + times[3 * SL];
        const float tot = intb[0] + intb[1] + intb[2] + intb[3] + I0 * t0s;
        out[0] = -(ll - tot);
    }
}

extern "C" void kernel_launch(void* const* d_in, const int* in_sizes, int n_in,
                              void* d_out, int out_size, void* d_ws, size_t ws_size,
                              hipStream_t stream) {
    const float* times    = (const float*)d_in[0];
    const int*   types    = (const int*)  d_in[1];
    const int*   cats     = (const int*)  d_in[2];
    const int*   Tp       = (const int*)  d_in[3];
    const float* type_emb = (const float*)d_in[4];
    const float* cat_emb  = (const float*)d_in[5];
    const float* amat     = (const float*)d_in[6];
    const float* bmat     = (const float*)d_in[7];
    const float* A        = (const float*)d_in[8];
    const float* P        = (const float*)d_in[9];
    const float* Bm       = (const float*)d_in[10];
    const float* Q        = (const float*)d_in[11];
    float* out = (float*)d_out;
    float* ws  = (float*)d_ws;

    // No memset: every ws plane slot read by hawkes_final is written exactly once.
    hawkes_main<<<MAIN_BLOCKS, NTHREADS, 0, stream>>>(times, types, cats, Tp,
                                                      type_emb, cat_emb, amat, bmat,
                                                      A, P, Bm, Q, ws);
    hawkes_final<<<1, 256, 0, stream>>>(times, types, cats, Tp,
                                        type_emb, amat, bmat, ws, out);
}

// Round 8
// 98.501 us; speedup vs baseline: 1.2518x; 1.1453x over previous
//
#include <hip/hip_runtime.h>

#define NTYPES 50
#define NCATS  20
#define EDIM   64
#define BATCH  4
#define SEQL   256

// Blocks: 512 LL (b, pair{pr, 255-pr}) + 200 IT (b,t) + 4 IC (b) + 1 I0
#define LL_BLOCKS 512
#define IT_BLOCKS 200
#define IC_BLOCKS 4
#define TOTAL_BLOCKS 717

// ws float layout, every slot/counter on its own 128B (32-float) line:
//   value slot (target, g) at ws[(target*16+g)*32]; targets: 0=ll, 1..4=int_b, 5=I0
//   sub-counter g at ws[(96+g)*32]; top counter at ws[112*32]
#define SLOT(tgt, g) (((tgt) * 16 + (g)) * 32)
#define SUBC(g)      ((96 + (g)) * 32)
#define TOPC         (112 * 32)
#define WS_ZERO_BYTES ((112 * 32 + 1) * 4)

// Precomputed coefficient tables (beyond the zeroed region, 256KB-aligned):
//   CRt[(k*NTYPES+t)*EDIM+e] = {te*A*f, te*P*f}   (160000 float2, 1.28 MB)
//   CRc[(kc*NCATS+c)*EDIM+e] = {ce*Bm*g, ce*Q*g}  (25600  float2, 0.20 MB)
#define TBL_T_OFF 65536
#define NT_ELEMS  (NTYPES * NTYPES * EDIM)
#define NC_ELEMS  (NCATS * NCATS * EDIM)
#define TBL_C_OFF (TBL_T_OFF + 2 * NT_ELEMS)

__device__ __forceinline__ float softplusf(float x) {
    return (x > 0.f) ? x + log1pf(__expf(-x)) : log1pf(__expf(x));
}

__device__ __forceinline__ float waveReduceSum(float v) {
    #pragma unroll
    for (int off = 32; off > 0; off >>= 1) v += __shfl_down(v, off, 64);
    return v;
}

// Event-independent coefficient fusion: C=te*A*f, R=te*P*f keyed (k,tgt,e).
// Note A/P (and Bm/Q) have layout [K][TGT][E], so the element index i maps 1:1.
__global__ __launch_bounds__(256) void build_tables(
        const float* __restrict__ type_emb,
        const float* __restrict__ cat_emb,
        const float* __restrict__ A,
        const float* __restrict__ P,
        const float* __restrict__ Bm,
        const float* __restrict__ Q,
        float2* __restrict__ CRt,
        float2* __restrict__ CRc) {
    const int i = blockIdx.x * 256 + threadIdx.x;
    if (i < NT_ELEMS) {
        const int e = i & 63, kt = i >> 6;
        const int t = kt % NTYPES, k = kt / NTYPES;
        const float te = type_emb[t * EDIM + e];
        const float f  = type_emb[k * EDIM + e];
        CRt[i] = make_float2(te * A[i] * f, te * P[i] * f);
    } else if (i < NT_ELEMS + NC_ELEMS) {
        const int j = i - NT_ELEMS;
        const int e = j & 63, kc = j >> 6;
        const int c = kc % NCATS, k2 = kc / NCATS;
        const float ce = cat_emb[c * EDIM + e];
        const float g  = cat_emb[k2 * EDIM + e];
        CRc[j] = make_float2(ce * Bm[j] * g, ce * Q[j] * g);
    }
}

__global__ __launch_bounds__(256) void hawkes_fused(
        const float* __restrict__ times,
        const int*   __restrict__ types,
        const int*   __restrict__ cats,
        const int*   __restrict__ Tp,
        const float* __restrict__ type_emb,
        const float* __restrict__ cat_emb,
        const float* __restrict__ amat,
        const float* __restrict__ bmat,
        const float2* __restrict__ CRt,
        const float2* __restrict__ CRc,
        float* __restrict__ ws,
        float* __restrict__ out) {
    const int blk  = blockIdx.x;
    const int tid  = threadIdx.x;
    const int lane = tid & 63;
    const int wave = tid >> 6;
    const int g    = blk & 15;

    __shared__ float red1[4], red2[4];
    __shared__ float sn[4][EDIM];
    __shared__ float fin[96];
    __shared__ int   finflag;

    if (blk < LL_BLOCKS) {
        // ---- two events per block: i1 = pr (0..127), i2 = 255-pr (128..255) ----
        const int b  = blk >> 7;
        const int pr = blk & 127;
        const int i1 = pr, i2 = 255 - pr;
        const int base = b * SEQL;
        const int t1 = types[base + i1], t2 = types[base + i2];
        const int c2 = cats[base + i2 - 1];
        const int c1 = (i1 > 0) ? cats[base + i1 - 1] : 0;
        const float ti1 = times[base + i1], ti2 = times[base + i2];

        float acc1 = 0.f, acc2 = 0.f;
        // sources s ≡ wave (mod 4); s < i1 feeds both events, s in [i1,i2) only ev2
        #pragma unroll 4
        for (int s = wave; s < i1; s += 4) {
            const int   k  = types[base + s];
            const int   cs = cats [base + s];
            const float ts = times[base + s];
            const float2 t1v = CRt[(k  * NTYPES + t1) * EDIM + lane];
            const float2 t2v = CRt[(k  * NTYPES + t2) * EDIM + lane];
            const float2 c1v = CRc[(cs * NCATS  + c1) * EDIM + lane];
            const float2 c2v = CRc[(cs * NCATS  + c2) * EDIM + lane];
            const float td1 = ti1 - ts, td2 = ti2 - ts;
            acc1 += t1v.x * __expf(-t1v.y * td1) + c1v.x * __expf(-c1v.y * td1);
            acc2 += t2v.x * __expf(-t2v.y * td2) + c2v.x * __expf(-c2v.y * td2);
        }
        const int n1 = (i1 > wave) ? ((i1 - wave + 3) >> 2) : 0;
        #pragma unroll 4
        for (int s = wave + 4 * n1; s < i2; s += 4) {
            const int   k  = types[base + s];
            const int   cs = cats [base + s];
            const float ts = times[base + s];
            const float2 t2v = CRt[(k  * NTYPES + t2) * EDIM + lane];
            const float2 c2v = CRc[(cs * NCATS  + c2) * EDIM + lane];
            const float td2 = ti2 - ts;
            acc2 += t2v.x * __expf(-t2v.y * td2) + c2v.x * __expf(-c2v.y * td2);
        }
        if (wave == 0) {
            const float te1 = type_emb[t1 * EDIM + lane];
            if (i1 == 0) acc1 += softplusf(te1 * amat[t1 * EDIM + lane]);
            else         acc1 += te1 * (amat[t1 * EDIM + lane] + bmat[c1 * EDIM + lane]);
        } else if (wave == 1) {
            const float te2 = type_emb[t2 * EDIM + lane];
            acc2 += te2 * (amat[t2 * EDIM + lane] + bmat[c2 * EDIM + lane]);
        }
        const float r1 = waveReduceSum(acc1);
        const float r2 = waveReduceSum(acc2);
        if (lane == 0) { red1[wave] = r1; red2[wave] = r2; }
        __syncthreads();
        if (tid == 0) {
            const float lam1 = red1[0] + red1[1] + red1[2] + red1[3];
            const float lam2 = red2[0] + red2[1] + red2[2] + red2[3];
            atomicAdd(&ws[SLOT(0, g)], logf(lam1 + 1e-16f) + lam1
                                     + logf(lam2 + 1e-16f) + lam2);
        }
    } else if (blk < LL_BLOCKS + IT_BLOCKS) {
        // ---- horizon integral, type channel, (b, t) ----
        const int bt = blk - LL_BLOCKS;
        const int b = bt / NTYPES, t = bt % NTYPES;
        const int base = b * SEQL;
        const float Tf = (float)Tp[0];
        float acc = 0.f;
        #pragma unroll 4
        for (int s = wave; s < SEQL; s += 4) {
            const int   k  = types[base + s];
            const float td = Tf - times[base + s];
            const float2 v = CRt[(k * NTYPES + t) * EDIM + lane];
            acc += v.x * __expf(-v.y * td);
        }
        const float r = waveReduceSum(acc);
        if (lane == 0) red1[wave] = r;
        __syncthreads();
        if (tid == 0)
            atomicAdd(&ws[SLOT(1 + b, g)], red1[0] + red1[1] + red1[2] + red1[3]);
    } else if (blk < LL_BLOCKS + IT_BLOCKS + IC_BLOCKS) {
        // ---- horizon integral, category + base, per b ----
        const int b = blk - LL_BLOCKS - IT_BLOCKS;
        const int base = b * SEQL;
        const float Tf = (float)Tp[0];
        const int   lc = cats[base + SEQL - 1];
        float nacc = 0.f;
        #pragma unroll 4
        for (int s = wave; s < SEQL; s += 4) {
            const int   cs = cats[base + s];
            const float td = Tf - times[base + s];
            const float2 v = CRc[(cs * NCATS + lc) * EDIM + lane];
            nacc += v.x * __expf(-v.y * td);
        }
        sn[wave][lane] = nacc;
        __syncthreads();
        if (wave == 0) {
            const float n_e = sn[0][lane] + sn[1][lane] + sn[2][lane] + sn[3][lane];
            float TA = 0.f, TS = 0.f;
            for (int t = 0; t < NTYPES; ++t) {
                const float tv = type_emb[t * EDIM + lane];
                TA += tv * amat[t * EDIM + lane];
                TS += tv;
            }
            float term = TA + (bmat[lc * EDIM + lane] + n_e) * TS;
            term = waveReduceSum(term);
            if (lane == 0) atomicAdd(&ws[SLOT(1 + b, g)], term);
        }
    } else {
        // ---- I0 ----
        float acc = 0.f;
        for (int t = wave; t < NTYPES; t += 4)
            acc += softplusf(type_emb[t * EDIM + lane] * amat[t * EDIM + lane]);
        const float r = waveReduceSum(acc);
        if (lane == 0) red1[wave] = r;
        __syncthreads();
        if (tid == 0)
            atomicAdd(&ws[SLOT(5, g)], red1[0] + red1[1] + red1[2] + red1[3]);
    }

    // ---- hierarchical completion; atomics-only coherence ----
    if (tid == 0) {
        finflag = 0;
        __asm__ __volatile__("s_waitcnt vmcnt(0)" ::: "memory");
        const unsigned cnt_g = (unsigned)((TOTAL_BLOCKS + 15 - g) >> 4);
        unsigned old = atomicAdd((unsigned int*)&ws[SUBC(g)], 1u);
        if (old == cnt_g - 1u) {
            unsigned o2 = atomicAdd((unsigned int*)&ws[TOPC], 1u);
            if (o2 == 15u) finflag = 1;
        }
    }
    __syncthreads();
    if (finflag) {
        if (tid < 96) fin[tid] = atomicAdd(&ws[tid * 32], 0.f);
        __syncthreads();
        if (tid == 0) {
            float ll = 0.f, i0 = 0.f;
            for (int j = 0; j < 16; ++j) { ll += fin[j]; i0 += fin[80 + j]; }
            const float Tf = (float)Tp[0];
            float tot = 0.f;
            for (int b2 = 0; b2 < BATCH; ++b2) {
                float ib = 0.f;
                for (int j = 0; j < 16; ++j) ib += fin[(1 + b2) * 16 + j];
                tot += ib * (Tf - times[b2 * SEQL + SEQL - 1]) + i0 * times[b2 * SEQL];
            }
            out[0] = -(ll - tot);
        }
    }
}

extern "C" void kernel_launch(void* const* d_in, const int* in_sizes, int n_in,
                              void* d_out, int out_size, void* d_ws, size_t ws_size,
                              hipStream_t stream) {
    const float* times    = (const float*)d_in[0];
    const int*   types    = (const int*)  d_in[1];
    const int*   cats     = (const int*)  d_in[2];
    const int*   Tp       = (const int*)  d_in[3];
    const float* type_emb = (const float*)d_in[4];
    const float* cat_emb  = (const float*)d_in[5];
    const float* amat     = (const float*)d_in[6];
    const float* bmat     = (const float*)d_in[7];
    const float* A        = (const float*)d_in[8];
    const float* P        = (const float*)d_in[9];
    const float* Bm       = (const float*)d_in[10];
    const float* Q        = (const float*)d_in[11];
    float* out = (float*)d_out;
    float* ws  = (float*)d_ws;

    float2* CRt = (float2*)(ws + TBL_T_OFF);
    float2* CRc = (float2*)(ws + TBL_C_OFF);

    hipMemsetAsync(ws, 0, WS_ZERO_BYTES, stream);

    const int tbl_blocks = (NT_ELEMS + NC_ELEMS + 255) / 256;   // 726
    build_tables<<<tbl_blocks, 256, 0, stream>>>(type_emb, cat_emb,
                                                 A, P, Bm, Q, CRt, CRc);

    hawkes_fused<<<TOTAL_BLOCKS, 256, 0, stream>>>(times, types, cats, Tp,
                                                   type_emb, cat_emb, amat, bmat,
                                                   CRt, CRc, ws, out);
}

// Round 9
// 92.319 us; speedup vs baseline: 1.3356x; 1.0670x over previous
//
#include <hip/hip_runtime.h>

#define NTYPES 50
#define NCATS  20
#define EDIM   64
#define BATCH  4
#define SEQL   256

// Blocks: 512 LL (b, pair{pr, 255-pr}) + 200 IT (b,t) + 4 IC (b) + 1 I0
#define LL_BLOCKS 512
#define IT_BLOCKS 200
#define IC_BLOCKS 4
#define TOTAL_BLOCKS 717

// ws float layout, every slot/counter on its own 128B (32-float) line:
//   value slot (target, g) at ws[(target*16+g)*32]; targets: 0=ll, 1..4=int_b, 5=I0
//   sub-counter g at ws[(96+g)*32]; top counter at ws[112*32]
#define SLOT(tgt, g) (((tgt) * 16 + (g)) * 32)
#define SUBC(g)      ((96 + (g)) * 32)
#define TOPC         (112 * 32)
#define WS_ZERO_FLOATS (112 * 32 + 1)

// Precomputed coefficient tables (beyond the zeroed region, 256KB-aligned):
//   CRt[(k*NTYPES+t)*EDIM+e] = {te*A*f, te*P*f}   (160000 float2, 1.28 MB)
//   CRc[(kc*NCATS+c)*EDIM+e] = {ce*Bm*g, ce*Q*g}  (25600  float2, 0.20 MB)
#define TBL_T_OFF 65536
#define NT_ELEMS  (NTYPES * NTYPES * EDIM)
#define NC_ELEMS  (NCATS * NCATS * EDIM)
#define TBL_C_OFF (TBL_T_OFF + 2 * NT_ELEMS)
#define TBL_BLOCKS ((NT_ELEMS + NC_ELEMS + 255) / 256)   // 726

__device__ __forceinline__ float softplusf(float x) {
    return (x > 0.f) ? x + log1pf(__expf(-x)) : log1pf(__expf(x));
}

__device__ __forceinline__ float waveReduceSum(float v) {
    #pragma unroll
    for (int off = 32; off > 0; off >>= 1) v += __shfl_down(v, off, 64);
    return v;
}

// Event-independent coefficient fusion: C=te*A*f, R=te*P*f keyed (k,tgt,e).
// A/P (and Bm/Q) have layout [K][TGT][E], so element index i maps 1:1.
// The last block (TBL_BLOCKS) zeros the slot/counter region — fuses the
// hipMemsetAsync dispatch away.
__global__ __launch_bounds__(256) void build_tables(
        const float* __restrict__ type_emb,
        const float* __restrict__ cat_emb,
        const float* __restrict__ A,
        const float* __restrict__ P,
        const float* __restrict__ Bm,
        const float* __restrict__ Q,
        float2* __restrict__ CRt,
        float2* __restrict__ CRc,
        float* __restrict__ ws) {
    if (blockIdx.x == TBL_BLOCKS) {
        for (int j = threadIdx.x; j < WS_ZERO_FLOATS; j += 256) ws[j] = 0.f;
        return;
    }
    const int i = blockIdx.x * 256 + threadIdx.x;
    if (i < NT_ELEMS) {
        const int e = i & 63, kt = i >> 6;
        const int t = kt % NTYPES, k = kt / NTYPES;
        const float te = type_emb[t * EDIM + e];
        const float f  = type_emb[k * EDIM + e];
        CRt[i] = make_float2(te * A[i] * f, te * P[i] * f);
    } else if (i < NT_ELEMS + NC_ELEMS) {
        const int j = i - NT_ELEMS;
        const int e = j & 63, kc = j >> 6;
        const int c = kc % NCATS, k2 = kc / NCATS;
        const float ce = cat_emb[c * EDIM + e];
        const float g  = cat_emb[k2 * EDIM + e];
        CRc[j] = make_float2(ce * Bm[j] * g, ce * Q[j] * g);
    }
}

__global__ __launch_bounds__(256) void hawkes_fused(
        const float* __restrict__ times,
        const int*   __restrict__ types,
        const int*   __restrict__ cats,
        const int*   __restrict__ Tp,
        const float* __restrict__ type_emb,
        const float* __restrict__ cat_emb,
        const float* __restrict__ amat,
        const float* __restrict__ bmat,
        const float2* __restrict__ CRt,
        const float2* __restrict__ CRc,
        float* __restrict__ ws,
        float* __restrict__ out) {
    const int blk  = blockIdx.x;
    const int tid  = threadIdx.x;
    const int lane = tid & 63;
    const int wave = tid >> 6;
    const int g    = blk & 15;

    __shared__ float tsh[SEQL];
    __shared__ int   ysh[SEQL];
    __shared__ int   csh[SEQL];
    __shared__ float red1[4], red2[4];
    __shared__ float sn[4][EDIM];
    __shared__ float fin[96];
    __shared__ int   finflag;

    if (blk < LL_BLOCKS) {
        // ---- two events per block: i1 = pr (0..127), i2 = 255-pr (128..255) ----
        const int b  = blk >> 7;
        const int pr = blk & 127;
        const int i1 = pr, i2 = 255 - pr;
        const int base = b * SEQL;

        // stage this sequence once: inner loop reads become LDS broadcasts
        if (tid < SEQL) {
            tsh[tid] = times[base + tid];
            ysh[tid] = types[base + tid];
            csh[tid] = cats[base + tid];
        }
        __syncthreads();

        const int t1 = ysh[i1], t2 = ysh[i2];
        const int c2 = csh[i2 - 1];
        const int c1 = (i1 > 0) ? csh[i1 - 1] : 0;
        const float ti1 = tsh[i1], ti2 = tsh[i2];
        const int tb1 = t1 * EDIM + lane, tb2 = t2 * EDIM + lane;
        const int cb1 = c1 * EDIM + lane, cb2 = c2 * EDIM + lane;

        float acc1 = 0.f, acc2 = 0.f;
        // sources s ≡ wave (mod 4); s < i1 feeds both events, s in [i1,i2) only ev2
        #pragma unroll 4
        for (int s = wave; s < i1; s += 4) {
            const int   k  = ysh[s];
            const int   cs = csh[s];
            const float ts = tsh[s];
            const float2 t1v = CRt[k  * (NTYPES * EDIM) + tb1];
            const float2 t2v = CRt[k  * (NTYPES * EDIM) + tb2];
            const float2 c1v = CRc[cs * (NCATS  * EDIM) + cb1];
            const float2 c2v = CRc[cs * (NCATS  * EDIM) + cb2];
            const float td1 = ti1 - ts, td2 = ti2 - ts;
            acc1 += t1v.x * __expf(-t1v.y * td1) + c1v.x * __expf(-c1v.y * td1);
            acc2 += t2v.x * __expf(-t2v.y * td2) + c2v.x * __expf(-c2v.y * td2);
        }
        const int n1 = (i1 > wave) ? ((i1 - wave + 3) >> 2) : 0;
        #pragma unroll 4
        for (int s = wave + 4 * n1; s < i2; s += 4) {
            const int   k  = ysh[s];
            const int   cs = csh[s];
            const float ts = tsh[s];
            const float2 t2v = CRt[k  * (NTYPES * EDIM) + tb2];
            const float2 c2v = CRc[cs * (NCATS  * EDIM) + cb2];
            const float td2 = ti2 - ts;
            acc2 += t2v.x * __expf(-t2v.y * td2) + c2v.x * __expf(-c2v.y * td2);
        }
        if (wave == 0) {
            const float te1 = type_emb[t1 * EDIM + lane];
            if (i1 == 0) acc1 += softplusf(te1 * amat[t1 * EDIM + lane]);
            else         acc1 += te1 * (amat[t1 * EDIM + lane] + bmat[c1 * EDIM + lane]);
        } else if (wave == 1) {
            const float te2 = type_emb[t2 * EDIM + lane];
            acc2 += te2 * (amat[t2 * EDIM + lane] + bmat[c2 * EDIM + lane]);
        }
        const float r1 = waveReduceSum(acc1);
        const float r2 = waveReduceSum(acc2);
        if (lane == 0) { red1[wave] = r1; red2[wave] = r2; }
        __syncthreads();
        if (tid == 0) {
            const float lam1 = red1[0] + red1[1] + red1[2] + red1[3];
            const float lam2 = red2[0] + red2[1] + red2[2] + red2[3];
            atomicAdd(&ws[SLOT(0, g)], logf(lam1 + 1e-16f) + lam1
                                     + logf(lam2 + 1e-16f) + lam2);
        }
    } else if (blk < LL_BLOCKS + IT_BLOCKS) {
        // ---- horizon integral, type channel, (b, t) ----
        const int bt = blk - LL_BLOCKS;
        const int b = bt / NTYPES, t = bt % NTYPES;
        const int base = b * SEQL;
        const float Tf = (float)Tp[0];
        if (tid < SEQL) {
            tsh[tid] = times[base + tid];
            ysh[tid] = types[base + tid];
        }
        __syncthreads();
        const int tb = t * EDIM + lane;
        float acc = 0.f;
        #pragma unroll 4
        for (int s = wave; s < SEQL; s += 4) {
            const int   k  = ysh[s];
            const float td = Tf - tsh[s];
            const float2 v = CRt[k * (NTYPES * EDIM) + tb];
            acc += v.x * __expf(-v.y * td);
        }
        const float r = waveReduceSum(acc);
        if (lane == 0) red1[wave] = r;
        __syncthreads();
        if (tid == 0)
            atomicAdd(&ws[SLOT(1 + b, g)], red1[0] + red1[1] + red1[2] + red1[3]);
    } else if (blk < LL_BLOCKS + IT_BLOCKS + IC_BLOCKS) {
        // ---- horizon integral, category + base, per b ----
        const int b = blk - LL_BLOCKS - IT_BLOCKS;
        const int base = b * SEQL;
        const float Tf = (float)Tp[0];
        if (tid < SEQL) {
            tsh[tid] = times[base + tid];
            csh[tid] = cats[base + tid];
        }
        __syncthreads();
        const int lc = csh[SEQL - 1];
        const int cb = lc * EDIM + lane;
        float nacc = 0.f;
        #pragma unroll 4
        for (int s = wave; s < SEQL; s += 4) {
            const int   cs = csh[s];
            const float td = Tf - tsh[s];
            const float2 v = CRc[cs * (NCATS * EDIM) + cb];
            nacc += v.x * __expf(-v.y * td);
        }
        sn[wave][lane] = nacc;
        __syncthreads();
        if (wave == 0) {
            const float n_e = sn[0][lane] + sn[1][lane] + sn[2][lane] + sn[3][lane];
            float TA = 0.f, TS = 0.f;
            for (int t = 0; t < NTYPES; ++t) {
                const float tv = type_emb[t * EDIM + lane];
                TA += tv * amat[t * EDIM + lane];
                TS += tv;
            }
            float term = TA + (bmat[lc * EDIM + lane] + n_e) * TS;
            term = waveReduceSum(term);
            if (lane == 0) atomicAdd(&ws[SLOT(1 + b, g)], term);
        }
    } else {
        // ---- I0 ----
        float acc = 0.f;
        for (int t = wave; t < NTYPES; t += 4)
            acc += softplusf(type_emb[t * EDIM + lane] * amat[t * EDIM + lane]);
        const float r = waveReduceSum(acc);
        if (lane == 0) red1[wave] = r;
        __syncthreads();
        if (tid == 0)
            atomicAdd(&ws[SLOT(5, g)], red1[0] + red1[1] + red1[2] + red1[3]);
    }

    // ---- hierarchical completion; atomics-only coherence ----
    if (tid == 0) {
        finflag = 0;
        __asm__ __volatile__("s_waitcnt vmcnt(0)" ::: "memory");
        const unsigned cnt_g = (unsigned)((TOTAL_BLOCKS + 15 - g) >> 4);
        unsigned old = atomicAdd((unsigned int*)&ws[SUBC(g)], 1u);
        if (old == cnt_g - 1u) {
            unsigned o2 = atomicAdd((unsigned int*)&ws[TOPC], 1u);
            if (o2 == 15u) finflag = 1;
        }
    }
    __syncthreads();
    if (finflag) {
        if (tid < 96) fin[tid] = atomicAdd(&ws[tid * 32], 0.f);
        __syncthreads();
        if (tid == 0) {
            float ll = 0.f, i0 = 0.f;
            for (int j = 0; j < 16; ++j) { ll += fin[j]; i0 += fin[80 + j]; }
            const float Tf = (float)Tp[0];
            float tot = 0.f;
            for (int b2 = 0; b2 < BATCH; ++b2) {
                float ib = 0.f;
                for (int j = 0; j < 16; ++j) ib += fin[(1 + b2) * 16 + j];
                tot += ib * (Tf - times[b2 * SEQL + SEQL - 1]) + i0 * times[b2 * SEQL];
            }
            out[0] = -(ll - tot);
        }
    }
}

extern "C" void kernel_launch(void* const* d_in, const int* in_sizes, int n_in,
                              void* d_out, int out_size, void* d_ws, size_t ws_size,
                              hipStream_t stream) {
    const float* times    = (const float*)d_in[0];
    const int*   types    = (const int*)  d_in[1];
    const int*   cats     = (const int*)  d_in[2];
    const int*   Tp       = (const int*)  d_in[3];
    const float* type_emb = (const float*)d_in[4];
    const float* cat_emb  = (const float*)d_in[5];
    const float* amat     = (const float*)d_in[6];
    const float* bmat     = (const float*)d_in[7];
    const float* A        = (const float*)d_in[8];
    const float* P        = (const float*)d_in[9];
    const float* Bm       = (const float*)d_in[10];
    const float* Q        = (const float*)d_in[11];
    float* out = (float*)d_out;
    float* ws  = (float*)d_ws;

    float2* CRt = (float2*)(ws + TBL_T_OFF);
    float2* CRc = (float2*)(ws + TBL_C_OFF);

    // 2 dispatches total: build_tables (+ws zeroing in its extra block), main.
    build_tables<<<TBL_BLOCKS + 1, 256, 0, stream>>>(type_emb, cat_emb,
                                                     A, P, Bm, Q, CRt, CRc, ws);

    hawkes_fused<<<TOTAL_BLOCKS, 256, 0, stream>>>(times, types, cats, Tp,
                                                   type_emb, cat_emb, amat, bmat,
                                                   CRt, CRc, ws, out);
}